// Round 7
// baseline (128.557 us; speedup 1.0000x reference)
//
#include <hip/hip_runtime.h>

#define DIM 128
#define NN 72
#define BB 2
#define NSQ (NN*NN)        // 5184
#define NROWS (BB*NSQ)     // 10368
#define BN (BB*NN)         // 144
#define ZBLOCKS (NROWS/16) // 648

// ---------------------------------------------------------------------------
// Kernel 1: z = path@W_hz + b_hz (16 rows/blk, 512 thr: 2 rows x 2 cols per
// thread -> 8 waves/block, ~5 waves/SIMD). Also writes zT. Blocks 648..665
// compute P1/P3 = node@W1/W3.
// ---------------------------------------------------------------------------
__global__ __launch_bounds__(512, 4) void k_phase1(const float* __restrict__ path,
                                                   const float* __restrict__ Whz,
                                                   const float* __restrict__ bhz,
                                                   float* __restrict__ z,
                                                   float* __restrict__ zT,
                                                   const float* __restrict__ node,
                                                   const float* __restrict__ Wzz,
                                                   float* __restrict__ P1,
                                                   float* __restrict__ P3) {
    __shared__ float rows[16 * DIM];   // 8 KB
    const int t = threadIdx.x;

    if (blockIdx.x < ZBLOCKS) {
        const int r0 = blockIdx.x * 16;
        {
            float4* rs = (float4*)rows;
            const float4* pg = (const float4*)(path + r0 * DIM);
            rs[t] = pg[t];             // 512 float4 = 16*128 floats
        }
        __syncthreads();

        const int e2 = t & 63;         // 2 output cols
        const int rg = t >> 6;         // 0..7; rows rg and rg+8
        float2 bz = *(const float2*)&bhz[2 * e2];
        float2 acc[2] = {bz, bz};

        const float* Wp = Whz + 2 * e2;
        float2 w0[4], w1[4], n0[4], n1[4];
#pragma unroll
        for (int dd = 0; dd < 4; dd++) {
            w0[dd] = *(const float2*)&Wp[dd * DIM];
            w1[dd] = *(const float2*)&Wp[(4 + dd) * DIM];
        }
        for (int d8 = 0; d8 < 16; d8++) {
            if (d8 < 15) {
#pragma unroll
                for (int dd = 0; dd < 4; dd++) {
                    n0[dd] = *(const float2*)&Wp[(8 * d8 + 8 + dd) * DIM];
                    n1[dd] = *(const float2*)&Wp[(8 * d8 + 12 + dd) * DIM];
                }
            }
            float4 pa[2], pb[2];
#pragma unroll
            for (int r = 0; r < 2; r++) {
                pa[r] = *(const float4*)&rows[(rg + 8 * r) * DIM + 8 * d8];
                pb[r] = *(const float4*)&rows[(rg + 8 * r) * DIM + 8 * d8 + 4];
            }
#pragma unroll
            for (int dd = 0; dd < 4; dd++)
#pragma unroll
                for (int r = 0; r < 2; r++) {
                    float pv = ((const float*)&pa[r])[dd];
                    acc[r].x = fmaf(pv, w0[dd].x, acc[r].x);
                    acc[r].y = fmaf(pv, w0[dd].y, acc[r].y);
                }
#pragma unroll
            for (int dd = 0; dd < 4; dd++)
#pragma unroll
                for (int r = 0; r < 2; r++) {
                    float pv = ((const float*)&pb[r])[dd];
                    acc[r].x = fmaf(pv, w1[dd].x, acc[r].x);
                    acc[r].y = fmaf(pv, w1[dd].y, acc[r].y);
                }
#pragma unroll
            for (int dd = 0; dd < 4; dd++) { w0[dd] = n0[dd]; w1[dd] = n1[dd]; }
        }
#pragma unroll
        for (int r = 0; r < 2; r++) {
            int row = r0 + rg + 8 * r;
            *(float2*)&z[row * DIM + 2 * e2] = acc[r];
            int b  = row / NSQ;
            int ij = row - b * NSQ;
            int i  = ij / NN;
            int j  = ij - i * NN;
            *(float2*)&zT[(b * NSQ + j * NN + i) * DIM + 2 * e2] = acc[r];
        }
    } else {
        const int r0 = (blockIdx.x - ZBLOCKS) * 8;
        if (t < 256) {
            float4* rs = (float4*)rows;
            const float4* ng = (const float4*)(node + r0 * DIM);
            rs[t] = ng[t];             // 8*128 floats
        }
        __syncthreads();
        const int e  = t & 127;
        const int rr = t >> 7;         // 0..3; rows rr, rr+4
        float a1[2] = {0.f, 0.f};
        float a3[2] = {0.f, 0.f};
        const float* W1 = Wzz + e;
        const float* W3 = Wzz + 2 * DIM * DIM + e;
        for (int d = 0; d < DIM; d++) {
            float w1 = W1[d * DIM];
            float w3 = W3[d * DIM];
#pragma unroll
            for (int s = 0; s < 2; s++) {
                float pv = rows[(rr + 4 * s) * DIM + d];
                a1[s] = fmaf(pv, w1, a1[s]);
                a3[s] = fmaf(pv, w3, a3[s]);
            }
        }
#pragma unroll
        for (int s = 0; s < 2; s++) {
            int m = r0 + rr + 4 * s;
            P1[m * DIM + e] = a1[s];
            P3[m * DIM + e] = a3[s];
        }
    }
}

// ---------------------------------------------------------------------------
// Kernel 2: fused tropical conv + output GEMM, 512 threads.
// Phase 2: 4-way k-split (ty=t>>7), 18 k's each, groups of 2, LDS merge tree.
// Phase 3: 16-row GEMM, 2 rows x 2 cols per thread.
// ---------------------------------------------------------------------------
__global__ __launch_bounds__(512, 4) void k_trop_out(
        const float* __restrict__ z,   const float* __restrict__ zT,
        const float* __restrict__ Wzz, const float* __restrict__ bzz,
        const float* __restrict__ P1,  const float* __restrict__ P3,
        float* __restrict__ out) {
    __shared__ float rows[16 * DIM];      // zmax tile (8 KB)
    __shared__ float comb[3][16 * DIM];   // partials from ty=1..3 (24 KB)
    const int t   = threadIdx.x;
    const int blk = blockIdx.x;
    const int b   = blk / 324;
    const int rem = blk - b * 324;
    const int it  = rem / 18;
    const int jt  = rem - it * 18;
    const int i0 = it * 4, j0 = jt * 4;
    const int d  = t & 127;
    const int ty = t >> 7;    // 0..3: k residue class
    const float* zb  = z  + b * NSQ * DIM;
    const float* zTb = zT + b * NSQ * DIM;

    // ---- phase 2: max-plus over k (k = ty + 4*m, m=0..17, groups of 2) ----
    {
        float acc[16];
#pragma unroll
        for (int q = 0; q < 16; q++) acc[q] = -3.402823466e38f;

        float cur[16], nxt[16];   // [kk*8 + s]: s=0..3 zi, 4..7 zj (kk=0,1)
#pragma unroll
        for (int kk = 0; kk < 2; kk++) {
            int k = ty + 4 * kk;
#pragma unroll
            for (int s = 0; s < 4; s++) {
                cur[kk * 8 + s]     = zb [((i0 + s) * NN + k) * DIM + d];
                cur[kk * 8 + 4 + s] = zTb[((j0 + s) * NN + k) * DIM + d];
            }
        }
        for (int g = 0; g < 9; g++) {
            if (g < 8) {
#pragma unroll
                for (int kk = 0; kk < 2; kk++) {
                    int k = ty + 4 * (2 * (g + 1) + kk);
#pragma unroll
                    for (int s = 0; s < 4; s++) {
                        nxt[kk * 8 + s]     = zb [((i0 + s) * NN + k) * DIM + d];
                        nxt[kk * 8 + 4 + s] = zTb[((j0 + s) * NN + k) * DIM + d];
                    }
                }
            }
#pragma unroll
            for (int kk = 0; kk < 2; kk++)
#pragma unroll
                for (int a = 0; a < 4; a++)
#pragma unroll
                    for (int c = 0; c < 4; c++)
                        acc[a * 4 + c] = fmaxf(acc[a * 4 + c],
                                               cur[kk * 8 + a] + cur[kk * 8 + 4 + c]);
#pragma unroll
            for (int q = 0; q < 16; q++) cur[q] = nxt[q];
        }

        if (ty > 0) {
#pragma unroll
            for (int q = 0; q < 16; q++) comb[ty - 1][q * DIM + d] = acc[q];
        }
        __syncthreads();
        if (ty == 0) {
#pragma unroll
            for (int a = 0; a < 4; a++)
#pragma unroll
                for (int c = 0; c < 4; c++) {
                    int q = a * 4 + c;
                    float m = acc[q];
                    m = fmaxf(m, comb[0][q * DIM + d]);
                    m = fmaxf(m, comb[1][q * DIM + d]);
                    m = fmaxf(m, comb[2][q * DIM + d]);
                    int idx = ((i0 + a) * NN + (j0 + c)) * DIM + d;
                    rows[q * DIM + d] = fmaxf(m, zb[idx]);
                }
        }
    }
    __syncthreads();

    // ---- phase 3: out = relu(zmax@W2 + P1[b,i] + P3[b,j] + b_zz) ----------
    {
        const int e2 = t & 63;
        const int rg = t >> 6;     // 0..7; LDS rows rg, rg+8
        float2 acc[2];
        acc[0] = make_float2(0.f, 0.f);
        acc[1] = make_float2(0.f, 0.f);

        const float* Wp = Wzz + DIM * DIM + 2 * e2;   // W2 block
        float2 w0[4], w1[4], n0[4], n1[4];
#pragma unroll
        for (int dd = 0; dd < 4; dd++) {
            w0[dd] = *(const float2*)&Wp[dd * DIM];
            w1[dd] = *(const float2*)&Wp[(4 + dd) * DIM];
        }
        for (int d8 = 0; d8 < 16; d8++) {
            if (d8 < 15) {
#pragma unroll
                for (int dd = 0; dd < 4; dd++) {
                    n0[dd] = *(const float2*)&Wp[(8 * d8 + 8 + dd) * DIM];
                    n1[dd] = *(const float2*)&Wp[(8 * d8 + 12 + dd) * DIM];
                }
            }
            float4 pa[2], pb[2];
#pragma unroll
            for (int r = 0; r < 2; r++) {
                pa[r] = *(const float4*)&rows[(rg + 8 * r) * DIM + 8 * d8];
                pb[r] = *(const float4*)&rows[(rg + 8 * r) * DIM + 8 * d8 + 4];
            }
#pragma unroll
            for (int dd = 0; dd < 4; dd++)
#pragma unroll
                for (int r = 0; r < 2; r++) {
                    float pv = ((const float*)&pa[r])[dd];
                    acc[r].x = fmaf(pv, w0[dd].x, acc[r].x);
                    acc[r].y = fmaf(pv, w0[dd].y, acc[r].y);
                }
#pragma unroll
            for (int dd = 0; dd < 4; dd++)
#pragma unroll
                for (int r = 0; r < 2; r++) {
                    float pv = ((const float*)&pb[r])[dd];
                    acc[r].x = fmaf(pv, w1[dd].x, acc[r].x);
                    acc[r].y = fmaf(pv, w1[dd].y, acc[r].y);
                }
#pragma unroll
            for (int dd = 0; dd < 4; dd++) { w0[dd] = n0[dd]; w1[dd] = n1[dd]; }
        }

        float2 bz = *(const float2*)&bzz[2 * e2];
#pragma unroll
        for (int r = 0; r < 2; r++) {
            int q = rg + 8 * r;        // LDS row index = a*4+c
            int a = q >> 2, c = q & 3;
            int orow = b * NSQ + (i0 + a) * NN + (j0 + c);
            float2 v1 = *(const float2*)&P1[(b * NN + i0 + a) * DIM + 2 * e2];
            float2 v3 = *(const float2*)&P3[(b * NN + j0 + c) * DIM + 2 * e2];
            float ox = fmaxf(acc[r].x + v1.x + v3.x + bz.x, 0.f);
            float oy = fmaxf(acc[r].y + v1.y + v3.y + bz.y, 0.f);
            *(float2*)&out[orow * DIM + 2 * e2] = make_float2(ox, oy);
        }
    }
}

extern "C" void kernel_launch(void* const* d_in, const int* in_sizes, int n_in,
                              void* d_out, int out_size, void* d_ws, size_t ws_size,
                              hipStream_t stream) {
    const float* node = (const float*)d_in[0];
    const float* path = (const float*)d_in[1];
    const float* Whz  = (const float*)d_in[2];
    const float* bhz  = (const float*)d_in[3];
    const float* Wzz  = (const float*)d_in[4];
    const float* bzz  = (const float*)d_in[5];
    float* out = (float*)d_out;

    float* z  = (float*)d_ws;
    float* zT = z  + NROWS * DIM;
    float* P1 = zT + NROWS * DIM;
    float* P3 = P1 + BN * DIM;

    hipLaunchKernelGGL(k_phase1,   dim3(ZBLOCKS + 18), dim3(512), 0, stream,
                       path, Whz, bhz, z, zT, node, Wzz, P1, P3);
    hipLaunchKernelGGL(k_trop_out, dim3(BB * 18 * 18), dim3(512), 0, stream,
                       z, zT, Wzz, bzz, P1, P3, out);
}

// Round 8
// 110.281 us; speedup vs baseline: 1.1657x; 1.1657x over previous
//
#include <hip/hip_runtime.h>

#define DIM 128
#define NN 72
#define BB 2
#define NSQ (NN*NN)        // 5184
#define NROWS (BB*NSQ)     // 10368
#define BN (BB*NN)         // 144
#define ZBLOCKS (NROWS/16) // 648
#define NODEBLK 9          // 144 rows / 16

// ---------------------------------------------------------------------------
// Kernel 1: blocks 0..8: P1/P3 = node@W1/W3 (16 rows/blk, same pipelined GEMM
// structure as z-blocks — fixes the serial-load-chain tail of R3..R6).
// Blocks 9..656: z = path@W_hz + b_hz (16 rows/blk) + zT write.
// Node blocks FIRST so they dispatch with the first wave and don't tail.
// ---------------------------------------------------------------------------
__global__ __launch_bounds__(256, 4) void k_phase1(const float* __restrict__ path,
                                                   const float* __restrict__ Whz,
                                                   const float* __restrict__ bhz,
                                                   float* __restrict__ z,
                                                   float* __restrict__ zT,
                                                   const float* __restrict__ node,
                                                   const float* __restrict__ Wzz,
                                                   float* __restrict__ P1,
                                                   float* __restrict__ P3) {
    __shared__ float rows[16 * DIM];   // 8 KB
    const int t = threadIdx.x;

    if (blockIdx.x >= NODEBLK) {
        // ---------------- z-GEMM: 16 path rows per block --------------------
        const int r0 = (blockIdx.x - NODEBLK) * 16;
        {
            float4* rs = (float4*)rows;
            const float4* pg = (const float4*)(path + r0 * DIM);
            rs[t]       = pg[t];
            rs[t + 256] = pg[t + 256];
        }
        __syncthreads();

        const int e2 = t & 63;
        const int rg = t >> 6;
        float2 bz = *(const float2*)&bhz[2 * e2];
        float2 acc[4];
#pragma unroll
        for (int r = 0; r < 4; r++) acc[r] = bz;

        const float* Wp = Whz + 2 * e2;
        float2 w0[4], w1[4], n0[4], n1[4];
#pragma unroll
        for (int dd = 0; dd < 4; dd++) {
            w0[dd] = *(const float2*)&Wp[dd * DIM];
            w1[dd] = *(const float2*)&Wp[(4 + dd) * DIM];
        }
        for (int d8 = 0; d8 < 16; d8++) {
            if (d8 < 15) {
#pragma unroll
                for (int dd = 0; dd < 4; dd++) {
                    n0[dd] = *(const float2*)&Wp[(8 * d8 + 8 + dd) * DIM];
                    n1[dd] = *(const float2*)&Wp[(8 * d8 + 12 + dd) * DIM];
                }
            }
            float4 pa[4], pb[4];
#pragma unroll
            for (int r = 0; r < 4; r++) {
                pa[r] = *(const float4*)&rows[(rg + 4 * r) * DIM + 8 * d8];
                pb[r] = *(const float4*)&rows[(rg + 4 * r) * DIM + 8 * d8 + 4];
            }
#pragma unroll
            for (int dd = 0; dd < 4; dd++)
#pragma unroll
                for (int r = 0; r < 4; r++) {
                    float pv = ((const float*)&pa[r])[dd];
                    acc[r].x = fmaf(pv, w0[dd].x, acc[r].x);
                    acc[r].y = fmaf(pv, w0[dd].y, acc[r].y);
                }
#pragma unroll
            for (int dd = 0; dd < 4; dd++)
#pragma unroll
                for (int r = 0; r < 4; r++) {
                    float pv = ((const float*)&pb[r])[dd];
                    acc[r].x = fmaf(pv, w1[dd].x, acc[r].x);
                    acc[r].y = fmaf(pv, w1[dd].y, acc[r].y);
                }
#pragma unroll
            for (int dd = 0; dd < 4; dd++) { w0[dd] = n0[dd]; w1[dd] = n1[dd]; }
        }
#pragma unroll
        for (int r = 0; r < 4; r++) {
            int row = r0 + rg + 4 * r;
            *(float2*)&z[row * DIM + 2 * e2] = acc[r];
            int b  = row / NSQ;
            int ij = row - b * NSQ;
            int i  = ij / NN;
            int j  = ij - i * NN;
            *(float2*)&zT[(b * NSQ + j * NN + i) * DIM + 2 * e2] = acc[r];
        }
    } else {
        // ---------------- node GEMM: 16 rows, both W1 and W3 ----------------
        const int r0 = blockIdx.x * 16;
        {
            float4* rs = (float4*)rows;
            const float4* ng = (const float4*)(node + r0 * DIM);
            rs[t]       = ng[t];
            rs[t + 256] = ng[t + 256];
        }
        __syncthreads();

        const int e2 = t & 63;
        const int rg = t >> 6;
        float2 a1[4], a3[4];
#pragma unroll
        for (int r = 0; r < 4; r++) {
            a1[r] = make_float2(0.f, 0.f);
            a3[r] = make_float2(0.f, 0.f);
        }

        const float* W1p = Wzz + 2 * e2;                  // W1 block
        const float* W3p = Wzz + 2 * DIM * DIM + 2 * e2;  // W3 block
        float2 u0[4], u1[4], v0[4], v1[4];   // current W1/W3 (8 K each)
        float2 un0[4], un1[4], vn0[4], vn1[4];
#pragma unroll
        for (int dd = 0; dd < 4; dd++) {
            u0[dd] = *(const float2*)&W1p[dd * DIM];
            u1[dd] = *(const float2*)&W1p[(4 + dd) * DIM];
            v0[dd] = *(const float2*)&W3p[dd * DIM];
            v1[dd] = *(const float2*)&W3p[(4 + dd) * DIM];
        }
        for (int d8 = 0; d8 < 16; d8++) {
            if (d8 < 15) {
#pragma unroll
                for (int dd = 0; dd < 4; dd++) {
                    un0[dd] = *(const float2*)&W1p[(8 * d8 + 8 + dd) * DIM];
                    un1[dd] = *(const float2*)&W1p[(8 * d8 + 12 + dd) * DIM];
                    vn0[dd] = *(const float2*)&W3p[(8 * d8 + 8 + dd) * DIM];
                    vn1[dd] = *(const float2*)&W3p[(8 * d8 + 12 + dd) * DIM];
                }
            }
            float4 pa[4], pb[4];
#pragma unroll
            for (int r = 0; r < 4; r++) {
                pa[r] = *(const float4*)&rows[(rg + 4 * r) * DIM + 8 * d8];
                pb[r] = *(const float4*)&rows[(rg + 4 * r) * DIM + 8 * d8 + 4];
            }
#pragma unroll
            for (int dd = 0; dd < 4; dd++)
#pragma unroll
                for (int r = 0; r < 4; r++) {
                    float pv = ((const float*)&pa[r])[dd];
                    a1[r].x = fmaf(pv, u0[dd].x, a1[r].x);
                    a1[r].y = fmaf(pv, u0[dd].y, a1[r].y);
                    a3[r].x = fmaf(pv, v0[dd].x, a3[r].x);
                    a3[r].y = fmaf(pv, v0[dd].y, a3[r].y);
                }
#pragma unroll
            for (int dd = 0; dd < 4; dd++)
#pragma unroll
                for (int r = 0; r < 4; r++) {
                    float pv = ((const float*)&pb[r])[dd];
                    a1[r].x = fmaf(pv, u1[dd].x, a1[r].x);
                    a1[r].y = fmaf(pv, u1[dd].y, a1[r].y);
                    a3[r].x = fmaf(pv, v1[dd].x, a3[r].x);
                    a3[r].y = fmaf(pv, v1[dd].y, a3[r].y);
                }
#pragma unroll
            for (int dd = 0; dd < 4; dd++) {
                u0[dd] = un0[dd]; u1[dd] = un1[dd];
                v0[dd] = vn0[dd]; v1[dd] = vn1[dd];
            }
        }
#pragma unroll
        for (int r = 0; r < 4; r++) {
            int m = r0 + rg + 4 * r;
            *(float2*)&P1[m * DIM + 2 * e2] = a1[r];
            *(float2*)&P3[m * DIM + 2 * e2] = a3[r];
        }
    }
}

// ---------------------------------------------------------------------------
// Kernel 2 (R6-verified, unchanged): fused tropical conv + output GEMM.
// Phase 2 reads 8 k-sequential streams (zi from z, zj from zT), 4 k's per
// group per ty. Phase 3 GEMM sources zmax tile from LDS; W2 prefetch depth 2.
// ---------------------------------------------------------------------------
__global__ __launch_bounds__(256, 3) void k_trop_out(
        const float* __restrict__ z,   const float* __restrict__ zT,
        const float* __restrict__ Wzz, const float* __restrict__ bzz,
        const float* __restrict__ P1,  const float* __restrict__ P3,
        float* __restrict__ out) {
    __shared__ float rows[16 * DIM];   // zmax tile (8 KB)
    __shared__ float comb[16 * DIM];   // k-split merge (8 KB)
    const int t   = threadIdx.x;
    const int blk = blockIdx.x;
    const int b   = blk / 324;
    const int rem = blk - b * 324;
    const int it  = rem / 18;
    const int jt  = rem - it * 18;
    const int i0 = it * 4, j0 = jt * 4;
    const int d  = t & 127;
    const int ty = t >> 7;    // k parity
    const float* zb  = z  + b * NSQ * DIM;
    const float* zTb = zT + b * NSQ * DIM;

    {
        float acc[16];
#pragma unroll
        for (int q = 0; q < 16; q++) acc[q] = -3.402823466e38f;

        float cur[32], nxt[32];   // [kk*8 + s]: s=0..3 zi, 4..7 zj
#pragma unroll
        for (int kk = 0; kk < 4; kk++) {
            int k = ty + 2 * kk;
#pragma unroll
            for (int s = 0; s < 4; s++) {
                cur[kk * 8 + s]     = zb [((i0 + s) * NN + k) * DIM + d];
                cur[kk * 8 + 4 + s] = zTb[((j0 + s) * NN + k) * DIM + d];
            }
        }
        for (int g = 0; g < 9; g++) {
            if (g < 8) {
#pragma unroll
                for (int kk = 0; kk < 4; kk++) {
                    int k = ty + 2 * kk + 8 * (g + 1);
#pragma unroll
                    for (int s = 0; s < 4; s++) {
                        nxt[kk * 8 + s]     = zb [((i0 + s) * NN + k) * DIM + d];
                        nxt[kk * 8 + 4 + s] = zTb[((j0 + s) * NN + k) * DIM + d];
                    }
                }
            }
#pragma unroll
            for (int kk = 0; kk < 4; kk++)
#pragma unroll
                for (int a = 0; a < 4; a++)
#pragma unroll
                    for (int c = 0; c < 4; c++)
                        acc[a * 4 + c] = fmaxf(acc[a * 4 + c],
                                               cur[kk * 8 + a] + cur[kk * 8 + 4 + c]);
#pragma unroll
            for (int q = 0; q < 32; q++) cur[q] = nxt[q];
        }

        if (ty == 1) {
#pragma unroll
            for (int q = 0; q < 16; q++) comb[q * DIM + d] = acc[q];
        }
        __syncthreads();
        if (ty == 0) {
#pragma unroll
            for (int a = 0; a < 4; a++)
#pragma unroll
                for (int c = 0; c < 4; c++) {
                    int q = a * 4 + c;
                    float m = fmaxf(acc[q], comb[q * DIM + d]);
                    int idx = ((i0 + a) * NN + (j0 + c)) * DIM + d;
                    rows[q * DIM + d] = fmaxf(m, zb[idx]);
                }
        }
    }
    __syncthreads();

    {
        const int e2 = t & 63;
        const int rg = t >> 6;
        float2 acc[4];
#pragma unroll
        for (int r = 0; r < 4; r++) acc[r] = make_float2(0.f, 0.f);

        const float* Wp = Wzz + DIM * DIM + 2 * e2;   // W2 block
        float2 w0[4], w1[4], n0[4], n1[4];
#pragma unroll
        for (int dd = 0; dd < 4; dd++) {
            w0[dd] = *(const float2*)&Wp[dd * DIM];
            w1[dd] = *(const float2*)&Wp[(4 + dd) * DIM];
        }
        for (int d8 = 0; d8 < 16; d8++) {
            if (d8 < 15) {
#pragma unroll
                for (int dd = 0; dd < 4; dd++) {
                    n0[dd] = *(const float2*)&Wp[(8 * d8 + 8 + dd) * DIM];
                    n1[dd] = *(const float2*)&Wp[(8 * d8 + 12 + dd) * DIM];
                }
            }
            float4 pa[4], pb[4];
#pragma unroll
            for (int r = 0; r < 4; r++) {
                pa[r] = *(const float4*)&rows[(rg + 4 * r) * DIM + 8 * d8];
                pb[r] = *(const float4*)&rows[(rg + 4 * r) * DIM + 8 * d8 + 4];
            }
#pragma unroll
            for (int dd = 0; dd < 4; dd++)
#pragma unroll
                for (int r = 0; r < 4; r++) {
                    float pv = ((const float*)&pa[r])[dd];
                    acc[r].x = fmaf(pv, w0[dd].x, acc[r].x);
                    acc[r].y = fmaf(pv, w0[dd].y, acc[r].y);
                }
#pragma unroll
            for (int dd = 0; dd < 4; dd++)
#pragma unroll
                for (int r = 0; r < 4; r++) {
                    float pv = ((const float*)&pb[r])[dd];
                    acc[r].x = fmaf(pv, w1[dd].x, acc[r].x);
                    acc[r].y = fmaf(pv, w1[dd].y, acc[r].y);
                }
#pragma unroll
            for (int dd = 0; dd < 4; dd++) { w0[dd] = n0[dd]; w1[dd] = n1[dd]; }
        }

        float2 bz = *(const float2*)&bzz[2 * e2];
#pragma unroll
        for (int r = 0; r < 4; r++) {
            int q = rg + 4 * r;        // LDS row index = a*4+c
            int a = q >> 2, c = q & 3;
            int orow = b * NSQ + (i0 + a) * NN + (j0 + c);
            float2 v1 = *(const float2*)&P1[(b * NN + i0 + a) * DIM + 2 * e2];
            float2 v3 = *(const float2*)&P3[(b * NN + j0 + c) * DIM + 2 * e2];
            float ox = fmaxf(acc[r].x + v1.x + v3.x + bz.x, 0.f);
            float oy = fmaxf(acc[r].y + v1.y + v3.y + bz.y, 0.f);
            *(float2*)&out[orow * DIM + 2 * e2] = make_float2(ox, oy);
        }
    }
}

extern "C" void kernel_launch(void* const* d_in, const int* in_sizes, int n_in,
                              void* d_out, int out_size, void* d_ws, size_t ws_size,
                              hipStream_t stream) {
    const float* node = (const float*)d_in[0];
    const float* path = (const float*)d_in[1];
    const float* Whz  = (const float*)d_in[2];
    const float* bhz  = (const float*)d_in[3];
    const float* Wzz  = (const float*)d_in[4];
    const float* bzz  = (const float*)d_in[5];
    float* out = (float*)d_out;

    float* z  = (float*)d_ws;
    float* zT = z  + NROWS * DIM;
    float* P1 = zT + NROWS * DIM;
    float* P3 = P1 + BN * DIM;

    hipLaunchKernelGGL(k_phase1,   dim3(ZBLOCKS + NODEBLK), dim3(256), 0, stream,
                       path, Whz, bhz, z, zT, node, Wzz, P1, P3);
    hipLaunchKernelGGL(k_trop_out, dim3(BB * 18 * 18),      dim3(256), 0, stream,
                       z, zT, Wzz, bzz, P1, P3, out);
}

// Round 9
// 108.385 us; speedup vs baseline: 1.1861x; 1.0175x over previous
//
#include <hip/hip_runtime.h>

#define DIM 128
#define NN 72
#define BB 2
#define NSQ (NN*NN)        // 5184
#define NROWS (BB*NSQ)     // 10368
#define BN (BB*NN)         // 144
#define ZBLOCKS (NROWS/16) // 648
#define NODEBLK 9          // 144 rows / 16

// ---------------------------------------------------------------------------
// Kernel 1 (R8-verified, unchanged): blocks 0..8 node GEMM (P1/P3), blocks
// 9..656 z = path@W_hz + b_hz (16 rows/blk) + zT write.
// ---------------------------------------------------------------------------
__global__ __launch_bounds__(256, 4) void k_phase1(const float* __restrict__ path,
                                                   const float* __restrict__ Whz,
                                                   const float* __restrict__ bhz,
                                                   float* __restrict__ z,
                                                   float* __restrict__ zT,
                                                   const float* __restrict__ node,
                                                   const float* __restrict__ Wzz,
                                                   float* __restrict__ P1,
                                                   float* __restrict__ P3) {
    __shared__ float rows[16 * DIM];   // 8 KB
    const int t = threadIdx.x;

    if (blockIdx.x >= NODEBLK) {
        const int r0 = (blockIdx.x - NODEBLK) * 16;
        {
            float4* rs = (float4*)rows;
            const float4* pg = (const float4*)(path + r0 * DIM);
            rs[t]       = pg[t];
            rs[t + 256] = pg[t + 256];
        }
        __syncthreads();

        const int e2 = t & 63;
        const int rg = t >> 6;
        float2 bz = *(const float2*)&bhz[2 * e2];
        float2 acc[4];
#pragma unroll
        for (int r = 0; r < 4; r++) acc[r] = bz;

        const float* Wp = Whz + 2 * e2;
        float2 w0[4], w1[4], n0[4], n1[4];
#pragma unroll
        for (int dd = 0; dd < 4; dd++) {
            w0[dd] = *(const float2*)&Wp[dd * DIM];
            w1[dd] = *(const float2*)&Wp[(4 + dd) * DIM];
        }
        for (int d8 = 0; d8 < 16; d8++) {
            if (d8 < 15) {
#pragma unroll
                for (int dd = 0; dd < 4; dd++) {
                    n0[dd] = *(const float2*)&Wp[(8 * d8 + 8 + dd) * DIM];
                    n1[dd] = *(const float2*)&Wp[(8 * d8 + 12 + dd) * DIM];
                }
            }
            float4 pa[4], pb[4];
#pragma unroll
            for (int r = 0; r < 4; r++) {
                pa[r] = *(const float4*)&rows[(rg + 4 * r) * DIM + 8 * d8];
                pb[r] = *(const float4*)&rows[(rg + 4 * r) * DIM + 8 * d8 + 4];
            }
#pragma unroll
            for (int dd = 0; dd < 4; dd++)
#pragma unroll
                for (int r = 0; r < 4; r++) {
                    float pv = ((const float*)&pa[r])[dd];
                    acc[r].x = fmaf(pv, w0[dd].x, acc[r].x);
                    acc[r].y = fmaf(pv, w0[dd].y, acc[r].y);
                }
#pragma unroll
            for (int dd = 0; dd < 4; dd++)
#pragma unroll
                for (int r = 0; r < 4; r++) {
                    float pv = ((const float*)&pb[r])[dd];
                    acc[r].x = fmaf(pv, w1[dd].x, acc[r].x);
                    acc[r].y = fmaf(pv, w1[dd].y, acc[r].y);
                }
#pragma unroll
            for (int dd = 0; dd < 4; dd++) { w0[dd] = n0[dd]; w1[dd] = n1[dd]; }
        }
#pragma unroll
        for (int r = 0; r < 4; r++) {
            int row = r0 + rg + 4 * r;
            *(float2*)&z[row * DIM + 2 * e2] = acc[r];
            int b  = row / NSQ;
            int ij = row - b * NSQ;
            int i  = ij / NN;
            int j  = ij - i * NN;
            *(float2*)&zT[(b * NSQ + j * NN + i) * DIM + 2 * e2] = acc[r];
        }
    } else {
        const int r0 = blockIdx.x * 16;
        {
            float4* rs = (float4*)rows;
            const float4* ng = (const float4*)(node + r0 * DIM);
            rs[t]       = ng[t];
            rs[t + 256] = ng[t + 256];
        }
        __syncthreads();

        const int e2 = t & 63;
        const int rg = t >> 6;
        float2 a1[4], a3[4];
#pragma unroll
        for (int r = 0; r < 4; r++) {
            a1[r] = make_float2(0.f, 0.f);
            a3[r] = make_float2(0.f, 0.f);
        }

        const float* W1p = Wzz + 2 * e2;
        const float* W3p = Wzz + 2 * DIM * DIM + 2 * e2;
        float2 u0[4], u1[4], v0[4], v1[4];
        float2 un0[4], un1[4], vn0[4], vn1[4];
#pragma unroll
        for (int dd = 0; dd < 4; dd++) {
            u0[dd] = *(const float2*)&W1p[dd * DIM];
            u1[dd] = *(const float2*)&W1p[(4 + dd) * DIM];
            v0[dd] = *(const float2*)&W3p[dd * DIM];
            v1[dd] = *(const float2*)&W3p[(4 + dd) * DIM];
        }
        for (int d8 = 0; d8 < 16; d8++) {
            if (d8 < 15) {
#pragma unroll
                for (int dd = 0; dd < 4; dd++) {
                    un0[dd] = *(const float2*)&W1p[(8 * d8 + 8 + dd) * DIM];
                    un1[dd] = *(const float2*)&W1p[(8 * d8 + 12 + dd) * DIM];
                    vn0[dd] = *(const float2*)&W3p[(8 * d8 + 8 + dd) * DIM];
                    vn1[dd] = *(const float2*)&W3p[(8 * d8 + 12 + dd) * DIM];
                }
            }
            float4 pa[4], pb[4];
#pragma unroll
            for (int r = 0; r < 4; r++) {
                pa[r] = *(const float4*)&rows[(rg + 4 * r) * DIM + 8 * d8];
                pb[r] = *(const float4*)&rows[(rg + 4 * r) * DIM + 8 * d8 + 4];
            }
#pragma unroll
            for (int dd = 0; dd < 4; dd++)
#pragma unroll
                for (int r = 0; r < 4; r++) {
                    float pv = ((const float*)&pa[r])[dd];
                    a1[r].x = fmaf(pv, u0[dd].x, a1[r].x);
                    a1[r].y = fmaf(pv, u0[dd].y, a1[r].y);
                    a3[r].x = fmaf(pv, v0[dd].x, a3[r].x);
                    a3[r].y = fmaf(pv, v0[dd].y, a3[r].y);
                }
#pragma unroll
            for (int dd = 0; dd < 4; dd++)
#pragma unroll
                for (int r = 0; r < 4; r++) {
                    float pv = ((const float*)&pb[r])[dd];
                    a1[r].x = fmaf(pv, u1[dd].x, a1[r].x);
                    a1[r].y = fmaf(pv, u1[dd].y, a1[r].y);
                    a3[r].x = fmaf(pv, v1[dd].x, a3[r].x);
                    a3[r].y = fmaf(pv, v1[dd].y, a3[r].y);
                }
#pragma unroll
            for (int dd = 0; dd < 4; dd++) {
                u0[dd] = un0[dd]; u1[dd] = un1[dd];
                v0[dd] = vn0[dd]; v1[dd] = vn1[dd];
            }
        }
#pragma unroll
        for (int r = 0; r < 4; r++) {
            int m = r0 + rg + 4 * r;
            *(float2*)&P1[m * DIM + 2 * e2] = a1[r];
            *(float2*)&P3[m * DIM + 2 * e2] = a3[r];
        }
    }
}

// ---------------------------------------------------------------------------
// Kernel 2: fused tropical conv + output GEMM, 2x4 (i,j) tile -> 1296 blocks
// (5.1 blocks/CU, ~20 waves/CU = 2x TLP vs R8). Phase 2: 2-way k-split,
// even/odd two-buffer prefetch (distinct register sets, no rotation copies).
// Phase 3: 1 col/thread, 4 rows — W2 per-wave stream halves (32 KB).
// ---------------------------------------------------------------------------
__global__ __launch_bounds__(256, 4) void k_trop_out(
        const float* __restrict__ z,   const float* __restrict__ zT,
        const float* __restrict__ Wzz, const float* __restrict__ bzz,
        const float* __restrict__ P1,  const float* __restrict__ P3,
        float* __restrict__ out) {
    __shared__ float rows[8 * DIM];   // zmax tile (4 KB)
    __shared__ float comb[8 * DIM];   // k-split merge (4 KB)
    const int t   = threadIdx.x;
    const int blk = blockIdx.x;
    const int b   = blk / 648;
    const int rem = blk - b * 648;
    const int it  = rem / 18;         // 0..35
    const int jt  = rem - it * 18;    // 0..17
    const int i0 = it * 2, j0 = jt * 4;
    const int d  = t & 127;
    const int ty = t >> 7;            // k parity (wave-uniform)
    const float* zb  = z  + b * NSQ * DIM;
    const float* zTb = zT + b * NSQ * DIM;

    // ---- phase 2: max-plus over k = ty + 2*kk + 8*g (kk=0..3, g=0..8) -----
    {
        float acc[8];
#pragma unroll
        for (int q = 0; q < 8; q++) acc[q] = -3.402823466e38f;

        float A[24], B[24];   // [kk*6 + s]: s=0..1 zi, 2..5 zj

        auto loadg = [&](float* buf, int g) {
#pragma unroll
            for (int kk = 0; kk < 4; kk++) {
                int k = ty + 2 * kk + 8 * g;
#pragma unroll
                for (int s = 0; s < 2; s++)
                    buf[kk * 6 + s] = zb[((i0 + s) * NN + k) * DIM + d];
#pragma unroll
                for (int s = 0; s < 4; s++)
                    buf[kk * 6 + 2 + s] = zTb[((j0 + s) * NN + k) * DIM + d];
            }
        };
        auto compg = [&](const float* buf) {
#pragma unroll
            for (int kk = 0; kk < 4; kk++)
#pragma unroll
                for (int a = 0; a < 2; a++)
#pragma unroll
                    for (int c = 0; c < 4; c++)
                        acc[a * 4 + c] = fmaxf(acc[a * 4 + c],
                                               buf[kk * 6 + a] + buf[kk * 6 + 2 + c]);
        };

        loadg(A, 0);
        for (int g = 0; g < 8; g += 2) {
            loadg(B, g + 1);
            compg(A);
            loadg(A, g + 2);   // g+2 <= 8
            compg(B);
        }
        compg(A);              // g = 8

        if (ty == 1) {
#pragma unroll
            for (int q = 0; q < 8; q++) comb[q * DIM + d] = acc[q];
        }
        __syncthreads();
        if (ty == 0) {
#pragma unroll
            for (int a = 0; a < 2; a++)
#pragma unroll
                for (int c = 0; c < 4; c++) {
                    int q = a * 4 + c;
                    float m = fmaxf(acc[q], comb[q * DIM + d]);
                    int idx = ((i0 + a) * NN + (j0 + c)) * DIM + d;
                    rows[q * DIM + d] = fmaxf(m, zb[idx]);
                }
        }
    }
    __syncthreads();

    // ---- phase 3: out = relu(zmax@W2 + P1[b,i] + P3[b,j] + b_zz) ----------
    {
        const int e  = t & 127;        // output col
        const int rr = t >> 7;         // 0..1 -> tile rows rr*4 .. rr*4+3
        float a4[4] = {0.f, 0.f, 0.f, 0.f};

        const float* Wp = Wzz + DIM * DIM + e;   // W2 block, 1 col
        float w[8], wn[8];
#pragma unroll
        for (int dd = 0; dd < 8; dd++) w[dd] = Wp[dd * DIM];
        for (int d8 = 0; d8 < 16; d8++) {
            if (d8 < 15) {
#pragma unroll
                for (int dd = 0; dd < 8; dd++)
                    wn[dd] = Wp[(8 * d8 + 8 + dd) * DIM];
            }
#pragma unroll
            for (int dd = 0; dd < 8; dd++)
#pragma unroll
                for (int s = 0; s < 4; s++)
                    a4[s] = fmaf(rows[(rr * 4 + s) * DIM + 8 * d8 + dd], w[dd], a4[s]);
#pragma unroll
            for (int dd = 0; dd < 8; dd++) w[dd] = wn[dd];
        }

        float bz = bzz[e];
#pragma unroll
        for (int s = 0; s < 4; s++) {
            int q = rr * 4 + s;        // tile row = a*4+c
            int a = q >> 2, c = q & 3;
            int orow = b * NSQ + (i0 + a) * NN + (j0 + c);
            float v1 = P1[(b * NN + i0 + a) * DIM + e];
            float v3 = P3[(b * NN + j0 + c) * DIM + e];
            out[orow * DIM + e] = fmaxf(a4[s] + v1 + v3 + bz, 0.f);
        }
    }
}

extern "C" void kernel_launch(void* const* d_in, const int* in_sizes, int n_in,
                              void* d_out, int out_size, void* d_ws, size_t ws_size,
                              hipStream_t stream) {
    const float* node = (const float*)d_in[0];
    const float* path = (const float*)d_in[1];
    const float* Whz  = (const float*)d_in[2];
    const float* bhz  = (const float*)d_in[3];
    const float* Wzz  = (const float*)d_in[4];
    const float* bzz  = (const float*)d_in[5];
    float* out = (float*)d_out;

    float* z  = (float*)d_ws;
    float* zT = z  + NROWS * DIM;
    float* P1 = zT + NROWS * DIM;
    float* P3 = P1 + BN * DIM;

    hipLaunchKernelGGL(k_phase1,   dim3(ZBLOCKS + NODEBLK), dim3(256), 0, stream,
                       path, Whz, bhz, z, zT, node, Wzz, P1, P3);
    hipLaunchKernelGGL(k_trop_out, dim3(BB * 36 * 18),      dim3(256), 0, stream,
                       z, zT, Wzz, bzz, P1, P3, out);
}